// Round 1
// baseline (299.699 us; speedup 1.0000x reference)
//
#include <hip/hip_runtime.h>
#include <math.h>

#define B_SZ 512
#define C_SZ 100000
#define H_PARAM 0.333f
#define S_PARAM 64.0f
#define M_PARAM 0.4f
#define EPS 1e-6f
#define PI_F 3.14159265358979323846f

__device__ inline float waveReduceSum(float v) {
#pragma unroll
    for (int off = 32; off > 0; off >>= 1) v += __shfl_xor(v, off, 64);
    return v;
}

// Kernel A: norms stats + per-row margin params (1 block, 512 threads)
__global__ __launch_bounds__(512) void stats_kernel(
    const float* __restrict__ norms,
    float* __restrict__ g_ang,
    float* __restrict__ g_add) {
    __shared__ float sh[8];
    int i = threadIdx.x;
    float n = fminf(fmaxf(norms[i], 0.001f), 100.0f);

    int wave = i >> 6, lane = i & 63;
    float wsum = waveReduceSum(n);
    if (lane == 0) sh[wave] = wsum;
    __syncthreads();
    float total = 0.f;
#pragma unroll
    for (int w = 0; w < 8; ++w) total += sh[w];
    float mean = total * (1.0f / 512.0f);
    __syncthreads();  // before reusing sh

    float d = n - mean;
    float wss = waveReduceSum(d * d);
    if (lane == 0) sh[wave] = wss;
    __syncthreads();
    float tss = 0.f;
#pragma unroll
    for (int w = 0; w < 8; ++w) tss += sh[w];
    float sd = sqrtf(tss / 511.0f);  // ddof=1

    float ms = (n - mean) / (sd + EPS) * H_PARAM;
    ms = fminf(fmaxf(ms, -1.0f), 1.0f);
    g_ang[i] = -M_PARAM * ms;
    g_add[i] = M_PARAM + M_PARAM * ms;
}

// Kernel B: one block per row; online sum of exp(v - 64) over C
__global__ __launch_bounds__(256) void row_kernel(
    const float* __restrict__ logits,
    const int* __restrict__ labels,
    const float* __restrict__ g_ang,
    const float* __restrict__ g_add,
    float* __restrict__ nll) {
    int row = blockIdx.x;
    int label = labels[row];
    const float* lr = logits + (size_t)row * C_SZ;

    __shared__ float s_target;
    __shared__ float shl[4];
    if (threadIdx.x == 0) {
        float c = lr[label];
        c = fminf(fmaxf(c, -1.0f + EPS), 1.0f - EPS);
        float theta = acosf(c);
        float tm = theta + g_ang[row];
        tm = fminf(fmaxf(tm, EPS), PI_F - EPS);
        s_target = (cosf(tm) - g_add[row]) * S_PARAM;
    }
    __syncthreads();
    float target = s_target;

    float l = 0.f;
    const float4* lr4 = (const float4*)lr;
    const int nchunk = C_SZ / 4;  // 25000, exact
    for (int j4 = threadIdx.x; j4 < nchunk; j4 += 256) {
        float4 v = lr4[j4];
        int jbase = j4 * 4;
        float vals[4] = {v.x, v.y, v.z, v.w};
#pragma unroll
        for (int k = 0; k < 4; ++k) {
            float c = fminf(fmaxf(vals[k], -1.0f + EPS), 1.0f - EPS);
            float sc = S_PARAM * c - S_PARAM;  // v - 64 (fixed-max logsumexp)
            if (jbase + k == label) sc = target - S_PARAM;
            l += __expf(sc);
        }
    }

    float lsum = waveReduceSum(l);
    int wave = threadIdx.x >> 6, lane = threadIdx.x & 63;
    if (lane == 0) shl[wave] = lsum;
    __syncthreads();
    if (threadIdx.x == 0) {
        float t = shl[0] + shl[1] + shl[2] + shl[3];
        nll[row] = S_PARAM + logf(t) - target;
    }
}

// Kernel C: mean over 512 rows -> scalar
__global__ __launch_bounds__(512) void mean_kernel(
    const float* __restrict__ nll,
    float* __restrict__ out) {
    __shared__ float sh[8];
    int i = threadIdx.x;
    float v = nll[i];
    int wave = i >> 6, lane = i & 63;
    float wsum = waveReduceSum(v);
    if (lane == 0) sh[wave] = wsum;
    __syncthreads();
    if (i == 0) {
        float total = 0.f;
#pragma unroll
        for (int w = 0; w < 8; ++w) total += sh[w];
        out[0] = total * (1.0f / 512.0f);
    }
}

extern "C" void kernel_launch(void* const* d_in, const int* in_sizes, int n_in,
                              void* d_out, int out_size, void* d_ws, size_t ws_size,
                              hipStream_t stream) {
    const float* logits = (const float*)d_in[0];
    const float* norms  = (const float*)d_in[1];
    const int*   labels = (const int*)d_in[2];
    float* out = (float*)d_out;

    float* g_ang = (float*)d_ws;            // 512 floats
    float* g_add = g_ang + B_SZ;            // 512 floats
    float* nll   = g_add + B_SZ;            // 512 floats

    stats_kernel<<<1, 512, 0, stream>>>(norms, g_ang, g_add);
    row_kernel<<<B_SZ, 256, 0, stream>>>(logits, labels, g_ang, g_add, nll);
    mean_kernel<<<1, 512, 0, stream>>>(nll, out);
}

// Round 2
// 289.544 us; speedup vs baseline: 1.0351x; 1.0351x over previous
//
#include <hip/hip_runtime.h>
#include <math.h>

#define B_SZ 512
#define C_SZ 100000
#define H_PARAM 0.333f
#define S_PARAM 64.0f
#define M_PARAM 0.4f
#define EPS 1e-6f
#define PI_F 3.14159265358979323846f

#define CHUNKS_PER_ROW 4
#define F4_PER_ROW (C_SZ / 4)              // 25000
#define F4_PER_CHUNK (F4_PER_ROW / CHUNKS_PER_ROW)  // 6250

__device__ inline float waveReduceSum(float v) {
#pragma unroll
    for (int off = 32; off > 0; off >>= 1) v += __shfl_xor(v, off, 64);
    return v;
}

__device__ inline float clip1(float x) {
    return fminf(fmaxf(x, -1.0f + EPS), 1.0f - EPS);
}

// Kernel A (1 block, 512 threads): norm stats, per-row target logit,
// per-row plain exp value at the label, and zero the accumulators.
__global__ __launch_bounds__(512) void stats_kernel(
    const float* __restrict__ norms,
    const float* __restrict__ logits,
    const int* __restrict__ labels,
    float* __restrict__ target,
    float* __restrict__ plain,
    float* __restrict__ acc) {
    __shared__ float sh[8];
    int i = threadIdx.x;
    float n = fminf(fmaxf(norms[i], 0.001f), 100.0f);

    int wave = i >> 6, lane = i & 63;
    float wsum = waveReduceSum(n);
    if (lane == 0) sh[wave] = wsum;
    __syncthreads();
    float total = 0.f;
#pragma unroll
    for (int w = 0; w < 8; ++w) total += sh[w];
    float mean = total * (1.0f / 512.0f);
    __syncthreads();

    float d = n - mean;
    float wss = waveReduceSum(d * d);
    if (lane == 0) sh[wave] = wss;
    __syncthreads();
    float tss = 0.f;
#pragma unroll
    for (int w = 0; w < 8; ++w) tss += sh[w];
    float sd = sqrtf(tss / 511.0f);  // ddof=1

    float ms = (n - mean) / (sd + EPS) * H_PARAM;
    ms = fminf(fmaxf(ms, -1.0f), 1.0f);
    float g_ang = -M_PARAM * ms;
    float g_add = M_PARAM + M_PARAM * ms;

    int lab = labels[i];
    float c = clip1(logits[(size_t)i * C_SZ + lab]);
    float theta = acosf(c);
    float tm = fminf(fmaxf(theta + g_ang, EPS), PI_F - EPS);
    float t = (cosf(tm) - g_add) * S_PARAM;

    target[i] = t;
    plain[i] = __expf(S_PARAM * c - S_PARAM);
    acc[i] = 0.f;
}

// Kernel B (B*4 blocks, 256 threads): partial sum of exp(64*clip(x)-64)
// over one quarter-row; one atomicAdd per block.
__global__ __launch_bounds__(256) void row_kernel(
    const float* __restrict__ logits,
    float* __restrict__ acc) {
    int row = blockIdx.x >> 2;
    int chunk = blockIdx.x & 3;
    const float4* lr4 = (const float4*)(logits + (size_t)row * C_SZ);
    int begin = chunk * F4_PER_CHUNK;
    int end = begin + F4_PER_CHUNK;

    float l = 0.f;
    for (int j = begin + threadIdx.x; j < end; j += 256) {
        float4 v = lr4[j];
        l += __expf(fmaf(S_PARAM, clip1(v.x), -S_PARAM));
        l += __expf(fmaf(S_PARAM, clip1(v.y), -S_PARAM));
        l += __expf(fmaf(S_PARAM, clip1(v.z), -S_PARAM));
        l += __expf(fmaf(S_PARAM, clip1(v.w), -S_PARAM));
    }

    __shared__ float shl[4];
    int wave = threadIdx.x >> 6, lane = threadIdx.x & 63;
    float wsum = waveReduceSum(l);
    if (lane == 0) shl[wave] = wsum;
    __syncthreads();
    if (threadIdx.x == 0) {
        atomicAdd(&acc[row], shl[0] + shl[1] + shl[2] + shl[3]);
    }
}

// Kernel C (1 block, 512 threads): label fix-up + nll + mean.
__global__ __launch_bounds__(512) void final_kernel(
    const float* __restrict__ acc,
    const float* __restrict__ target,
    const float* __restrict__ plain,
    float* __restrict__ out) {
    __shared__ float sh[8];
    int i = threadIdx.x;
    float t = target[i];
    float s = acc[i] - plain[i] + __expf(t - S_PARAM);
    float v = S_PARAM + logf(s) - t;

    int wave = i >> 6, lane = i & 63;
    float wsum = waveReduceSum(v);
    if (lane == 0) sh[wave] = wsum;
    __syncthreads();
    if (i == 0) {
        float total = 0.f;
#pragma unroll
        for (int w = 0; w < 8; ++w) total += sh[w];
        out[0] = total * (1.0f / 512.0f);
    }
}

extern "C" void kernel_launch(void* const* d_in, const int* in_sizes, int n_in,
                              void* d_out, int out_size, void* d_ws, size_t ws_size,
                              hipStream_t stream) {
    const float* logits = (const float*)d_in[0];
    const float* norms  = (const float*)d_in[1];
    const int*   labels = (const int*)d_in[2];
    float* out = (float*)d_out;

    float* target = (float*)d_ws;      // 512
    float* plain  = target + B_SZ;     // 512
    float* acc    = plain + B_SZ;      // 512

    stats_kernel<<<1, 512, 0, stream>>>(norms, logits, labels, target, plain, acc);
    row_kernel<<<B_SZ * CHUNKS_PER_ROW, 256, 0, stream>>>(logits, acc);
    final_kernel<<<1, 512, 0, stream>>>(acc, target, plain, out);
}

// Round 3
// 282.584 us; speedup vs baseline: 1.0606x; 1.0246x over previous
//
#include <hip/hip_runtime.h>
#include <math.h>

#define B_SZ 512
#define C_SZ 100000
#define H_PARAM 0.333f
#define S_PARAM 64.0f
#define M_PARAM 0.4f
#define EPS 1e-6f
#define PI_F 3.14159265358979323846f

#define CHUNKS_PER_ROW 8
#define F4_PER_ROW (C_SZ / 4)                        // 25000
#define F4_PER_CHUNK (F4_PER_ROW / CHUNKS_PER_ROW)   // 3125

__device__ inline float waveReduceSum(float v) {
#pragma unroll
    for (int off = 32; off > 0; off >>= 1) v += __shfl_xor(v, off, 64);
    return v;
}

__device__ inline float clip1(float x) {
    return fminf(fmaxf(x, -1.0f + EPS), 1.0f - EPS);
}

// Kernel B (B*8 blocks, 256 threads): partial sum of exp(64*clip(x)-64)
// over one eighth-row; plain store per block (no atomics, no init needed).
__global__ __launch_bounds__(256) void row_kernel(
    const float* __restrict__ logits,
    float* __restrict__ partial) {
    int row = blockIdx.x >> 3;
    int chunk = blockIdx.x & 7;
    const float4* lr4 = (const float4*)(logits + (size_t)row * C_SZ);
    int begin = chunk * F4_PER_CHUNK;
    int end = begin + F4_PER_CHUNK;

    float l = 0.f;
    for (int j = begin + threadIdx.x; j < end; j += 256) {
        float4 v = lr4[j];
        l += __expf(fmaf(S_PARAM, clip1(v.x), -S_PARAM));
        l += __expf(fmaf(S_PARAM, clip1(v.y), -S_PARAM));
        l += __expf(fmaf(S_PARAM, clip1(v.z), -S_PARAM));
        l += __expf(fmaf(S_PARAM, clip1(v.w), -S_PARAM));
    }

    __shared__ float shl[4];
    int wave = threadIdx.x >> 6, lane = threadIdx.x & 63;
    float wsum = waveReduceSum(l);
    if (lane == 0) shl[wave] = wsum;
    __syncthreads();
    if (threadIdx.x == 0) {
        partial[blockIdx.x] = shl[0] + shl[1] + shl[2] + shl[3];
    }
}

// Kernel C (1 block, 512 threads): norm stats + target + label fix-up +
// nll + batch mean, all fused.
__global__ __launch_bounds__(512) void final_kernel(
    const float* __restrict__ norms,
    const float* __restrict__ logits,
    const int* __restrict__ labels,
    const float* __restrict__ partial,
    float* __restrict__ out) {
    __shared__ float sh[8];
    int i = threadIdx.x;
    int wave = i >> 6, lane = i & 63;

    // --- norm statistics (mean, std ddof=1) ---
    float n = fminf(fmaxf(norms[i], 0.001f), 100.0f);
    float wsum = waveReduceSum(n);
    if (lane == 0) sh[wave] = wsum;
    __syncthreads();
    float total = 0.f;
#pragma unroll
    for (int w = 0; w < 8; ++w) total += sh[w];
    float mean = total * (1.0f / 512.0f);
    __syncthreads();

    float d = n - mean;
    float wss = waveReduceSum(d * d);
    if (lane == 0) sh[wave] = wss;
    __syncthreads();
    float tss = 0.f;
#pragma unroll
    for (int w = 0; w < 8; ++w) tss += sh[w];
    float sd = sqrtf(tss / 511.0f);
    __syncthreads();

    // --- per-row target logit ---
    float ms = (n - mean) / (sd + EPS) * H_PARAM;
    ms = fminf(fmaxf(ms, -1.0f), 1.0f);
    float g_ang = -M_PARAM * ms;
    float g_add = M_PARAM + M_PARAM * ms;

    int lab = labels[i];
    float c = clip1(logits[(size_t)i * C_SZ + lab]);
    float theta = acosf(c);
    float tm = fminf(fmaxf(theta + g_ang, EPS), PI_F - EPS);
    float t = (cosf(tm) - g_add) * S_PARAM;
    float plain = __expf(S_PARAM * c - S_PARAM);

    // --- combine partials + label fix-up ---
    float s = 0.f;
#pragma unroll
    for (int k = 0; k < CHUNKS_PER_ROW; ++k) s += partial[i * CHUNKS_PER_ROW + k];
    s = s - plain + __expf(t - S_PARAM);
    float v = S_PARAM + logf(s) - t;

    // --- batch mean ---
    float vsum = waveReduceSum(v);
    if (lane == 0) sh[wave] = vsum;
    __syncthreads();
    if (i == 0) {
        float tot = 0.f;
#pragma unroll
        for (int w = 0; w < 8; ++w) tot += sh[w];
        out[0] = tot * (1.0f / 512.0f);
    }
}

extern "C" void kernel_launch(void* const* d_in, const int* in_sizes, int n_in,
                              void* d_out, int out_size, void* d_ws, size_t ws_size,
                              hipStream_t stream) {
    const float* logits = (const float*)d_in[0];
    const float* norms  = (const float*)d_in[1];
    const int*   labels = (const int*)d_in[2];
    float* out = (float*)d_out;

    float* partial = (float*)d_ws;  // B_SZ * CHUNKS_PER_ROW floats

    row_kernel<<<B_SZ * CHUNKS_PER_ROW, 256, 0, stream>>>(logits, partial);
    final_kernel<<<1, 512, 0, stream>>>(norms, logits, labels, partial, out);
}

// Round 5
// 261.906 us; speedup vs baseline: 1.1443x; 1.0790x over previous
//
#include <hip/hip_runtime.h>
#include <math.h>

#define B_SZ 512
#define C_SZ 100000
#define H_PARAM 0.333f
#define S_PARAM 64.0f
#define M_PARAM 0.4f
#define EPS 1e-6f
#define PI_F 3.14159265358979323846f

#define CHUNKS_PER_ROW 8
#define F4_PER_ROW (C_SZ / 4)                        // 25000
#define F4_PER_CHUNK (F4_PER_ROW / CHUNKS_PER_ROW)   // 3125

typedef float nvec4 __attribute__((ext_vector_type(4)));  // native vector for nontemporal builtin

__device__ inline float waveReduceSum(float v) {
#pragma unroll
    for (int off = 32; off > 0; off >>= 1) v += __shfl_xor(v, off, 64);
    return v;
}

__device__ inline float clip1(float x) {
    return fminf(fmaxf(x, -1.0f + EPS), 1.0f - EPS);
}

// Row kernel (B*8 blocks, 256 threads): partial sum of exp(64*clip(x)-64)
// over one eighth-row. chunk-0 blocks additionally compute per-row
// target/plain (norm stats + label logit), overlapping the scattered label
// load with the streaming loop.
__global__ __launch_bounds__(256) void row_kernel(
    const float* __restrict__ logits,
    const float* __restrict__ norms,
    const int* __restrict__ labels,
    float* __restrict__ partial,
    float* __restrict__ target,
    float* __restrict__ plain) {
    int row = blockIdx.x >> 3;
    int chunk = blockIdx.x & 7;
    const nvec4* lr4 = (const nvec4*)(logits + (size_t)row * C_SZ);
    int begin = chunk * F4_PER_CHUNK;
    int end = begin + F4_PER_CHUNK;

    __shared__ float sh[4];
    int wave = threadIdx.x >> 6, lane = threadIdx.x & 63;

    // --- chunk-0: issue label load early, compute norm stats ---
    float c_raw = 0.f, g_ang = 0.f, g_add = 0.f;
    if (chunk == 0) {
        int lab = labels[row];
        c_raw = logits[(size_t)row * C_SZ + lab];  // scattered; overlaps loop

        float n0 = fminf(fmaxf(norms[threadIdx.x], 0.001f), 100.0f);
        float n1 = fminf(fmaxf(norms[threadIdx.x + 256], 0.001f), 100.0f);

        float wsum = waveReduceSum(n0 + n1);
        if (lane == 0) sh[wave] = wsum;
        __syncthreads();
        float mean = (sh[0] + sh[1] + sh[2] + sh[3]) * (1.0f / 512.0f);
        __syncthreads();

        float d0 = n0 - mean, d1 = n1 - mean;
        float wss = waveReduceSum(d0 * d0 + d1 * d1);
        if (lane == 0) sh[wave] = wss;
        __syncthreads();
        float sd = sqrtf((sh[0] + sh[1] + sh[2] + sh[3]) / 511.0f);  // ddof=1
        __syncthreads();

        // margin scaler for THIS row's norm
        float nr = fminf(fmaxf(norms[row], 0.001f), 100.0f);
        float ms = (nr - mean) / (sd + EPS) * H_PARAM;
        ms = fminf(fmaxf(ms, -1.0f), 1.0f);
        g_ang = -M_PARAM * ms;
        g_add = M_PARAM + M_PARAM * ms;
    }

    // --- streaming exp-sum (non-temporal: no reuse) ---
    float l = 0.f;
    for (int j = begin + threadIdx.x; j < end; j += 256) {
        nvec4 v = __builtin_nontemporal_load(lr4 + j);
        l += __expf(fmaf(S_PARAM, clip1(v.x), -S_PARAM));
        l += __expf(fmaf(S_PARAM, clip1(v.y), -S_PARAM));
        l += __expf(fmaf(S_PARAM, clip1(v.z), -S_PARAM));
        l += __expf(fmaf(S_PARAM, clip1(v.w), -S_PARAM));
    }

    float wsum = waveReduceSum(l);
    if (lane == 0) sh[wave] = wsum;
    __syncthreads();
    if (threadIdx.x == 0) {
        partial[blockIdx.x] = sh[0] + sh[1] + sh[2] + sh[3];
        if (chunk == 0) {
            float c = clip1(c_raw);
            float theta = acosf(c);
            float tm = fminf(fmaxf(theta + g_ang, EPS), PI_F - EPS);
            target[row] = (cosf(tm) - g_add) * S_PARAM;
            plain[row] = __expf(S_PARAM * c - S_PARAM);
        }
    }
}

// Final kernel (1 block, 512 threads): combine partials + label fix-up +
// nll + batch mean. All coalesced loads, ~2 us.
__global__ __launch_bounds__(512) void final_kernel(
    const float* __restrict__ partial,
    const float* __restrict__ target,
    const float* __restrict__ plain,
    float* __restrict__ out) {
    __shared__ float sh[8];
    int i = threadIdx.x;
    int wave = i >> 6, lane = i & 63;

    const float4* p4 = (const float4*)(partial + i * CHUNKS_PER_ROW);
    float4 a = p4[0], b = p4[1];
    float s = (a.x + a.y) + (a.z + a.w) + (b.x + b.y) + (b.z + b.w);

    float t = target[i];
    s = s - plain[i] + __expf(t - S_PARAM);
    float v = S_PARAM + logf(s) - t;

    float vsum = waveReduceSum(v);
    if (lane == 0) sh[wave] = vsum;
    __syncthreads();
    if (i == 0) {
        float tot = 0.f;
#pragma unroll
        for (int w = 0; w < 8; ++w) tot += sh[w];
        out[0] = tot * (1.0f / 512.0f);
    }
}

extern "C" void kernel_launch(void* const* d_in, const int* in_sizes, int n_in,
                              void* d_out, int out_size, void* d_ws, size_t ws_size,
                              hipStream_t stream) {
    const float* logits = (const float*)d_in[0];
    const float* norms  = (const float*)d_in[1];
    const int*   labels = (const int*)d_in[2];
    float* out = (float*)d_out;

    float* partial = (float*)d_ws;                    // B_SZ*8 floats
    float* target  = partial + B_SZ * CHUNKS_PER_ROW; // 512
    float* plain   = target + B_SZ;                   // 512

    row_kernel<<<B_SZ * CHUNKS_PER_ROW, 256, 0, stream>>>(
        logits, norms, labels, partial, target, plain);
    final_kernel<<<1, 512, 0, stream>>>(partial, target, plain, out);
}

// Round 6
// 259.590 us; speedup vs baseline: 1.1545x; 1.0089x over previous
//
#include <hip/hip_runtime.h>
#include <math.h>

#define B_SZ 512
#define C_SZ 100000
#define H_PARAM 0.333f
#define S_PARAM 64.0f
#define M_PARAM 0.4f
#define EPS 1e-6f
#define PI_F 3.14159265358979323846f

#define CHUNKS_PER_ROW 8
#define F4_PER_ROW (C_SZ / 4)                        // 25000
#define F4_PER_CHUNK (F4_PER_ROW / CHUNKS_PER_ROW)   // 3125 = 6*512 + 53

typedef float nvec4 __attribute__((ext_vector_type(4)));

__device__ inline float waveReduceSum(float v) {
#pragma unroll
    for (int off = 32; off > 0; off >>= 1) v += __shfl_xor(v, off, 64);
    return v;
}

__device__ inline float clip1(float x) {
    return fminf(fmaxf(x, -1.0f + EPS), 1.0f - EPS);
}

__device__ inline float exp4(nvec4 v) {
    float l = __expf(fmaf(S_PARAM, clip1(v.x), -S_PARAM));
    l += __expf(fmaf(S_PARAM, clip1(v.y), -S_PARAM));
    l += __expf(fmaf(S_PARAM, clip1(v.z), -S_PARAM));
    l += __expf(fmaf(S_PARAM, clip1(v.w), -S_PARAM));
    return l;
}

// Row kernel (B*8 blocks, 256 threads): partial sum of exp(64*clip(x)-64)
// over one eighth-row. 2-deep load pipeline: two float4 loads issued
// back-to-back per iteration to double in-flight bytes (L3-latency-bound
// regime — logits live in Infinity Cache after the harness restore-copy).
__global__ __launch_bounds__(256) void row_kernel(
    const float* __restrict__ logits,
    const float* __restrict__ norms,
    const int* __restrict__ labels,
    float* __restrict__ partial,
    float* __restrict__ target,
    float* __restrict__ plain) {
    int row = blockIdx.x >> 3;
    int chunk = blockIdx.x & 7;
    const nvec4* lr4 = (const nvec4*)(logits + (size_t)row * C_SZ);
    int begin = chunk * F4_PER_CHUNK;

    __shared__ float sh[4];
    int wave = threadIdx.x >> 6, lane = threadIdx.x & 63;

    // --- chunk-0: issue scattered label load early, compute norm stats ---
    float c_raw = 0.f, g_ang = 0.f, g_add = 0.f;
    if (chunk == 0) {
        int lab = labels[row];
        c_raw = logits[(size_t)row * C_SZ + lab];  // overlaps streaming loop

        float n0 = fminf(fmaxf(norms[threadIdx.x], 0.001f), 100.0f);
        float n1 = fminf(fmaxf(norms[threadIdx.x + 256], 0.001f), 100.0f);

        float wsum = waveReduceSum(n0 + n1);
        if (lane == 0) sh[wave] = wsum;
        __syncthreads();
        float mean = (sh[0] + sh[1] + sh[2] + sh[3]) * (1.0f / 512.0f);
        __syncthreads();

        float d0 = n0 - mean, d1 = n1 - mean;
        float wss = waveReduceSum(d0 * d0 + d1 * d1);
        if (lane == 0) sh[wave] = wss;
        __syncthreads();
        float sd = sqrtf((sh[0] + sh[1] + sh[2] + sh[3]) / 511.0f);  // ddof=1
        __syncthreads();

        float nr = fminf(fmaxf(norms[row], 0.001f), 100.0f);
        float ms = (nr - mean) / (sd + EPS) * H_PARAM;
        ms = fminf(fmaxf(ms, -1.0f), 1.0f);
        g_ang = -M_PARAM * ms;
        g_add = M_PARAM + M_PARAM * ms;
    }

    // --- streaming exp-sum, 2 float4 in flight per thread ---
    float l = 0.f;
    int j = begin + threadIdx.x;
#pragma unroll
    for (int it = 0; it < 6; ++it, j += 512) {
        nvec4 a = __builtin_nontemporal_load(lr4 + j);
        nvec4 b = __builtin_nontemporal_load(lr4 + j + 256);
        l += exp4(a);
        l += exp4(b);
    }
    if (threadIdx.x < (F4_PER_CHUNK - 6 * 512)) {  // 53-thread tail
        nvec4 a = __builtin_nontemporal_load(lr4 + j);
        l += exp4(a);
    }

    float wsum = waveReduceSum(l);
    if (lane == 0) sh[wave] = wsum;
    __syncthreads();
    if (threadIdx.x == 0) {
        partial[blockIdx.x] = sh[0] + sh[1] + sh[2] + sh[3];
        if (chunk == 0) {
            float c = clip1(c_raw);
            float theta = acosf(c);
            float tm = fminf(fmaxf(theta + g_ang, EPS), PI_F - EPS);
            target[row] = (cosf(tm) - g_add) * S_PARAM;
            plain[row] = __expf(S_PARAM * c - S_PARAM);
        }
    }
}

// Final kernel (1 block, 512 threads): combine partials + label fix-up +
// nll + batch mean.
__global__ __launch_bounds__(512) void final_kernel(
    const float* __restrict__ partial,
    const float* __restrict__ target,
    const float* __restrict__ plain,
    float* __restrict__ out) {
    __shared__ float sh[8];
    int i = threadIdx.x;
    int wave = i >> 6, lane = i & 63;

    const float4* p4 = (const float4*)(partial + i * CHUNKS_PER_ROW);
    float4 a = p4[0], b = p4[1];
    float s = (a.x + a.y) + (a.z + a.w) + (b.x + b.y) + (b.z + b.w);

    float t = target[i];
    s = s - plain[i] + __expf(t - S_PARAM);
    float v = S_PARAM + logf(s) - t;

    float vsum = waveReduceSum(v);
    if (lane == 0) sh[wave] = vsum;
    __syncthreads();
    if (i == 0) {
        float tot = 0.f;
#pragma unroll
        for (int w = 0; w < 8; ++w) tot += sh[w];
        out[0] = tot * (1.0f / 512.0f);
    }
}

extern "C" void kernel_launch(void* const* d_in, const int* in_sizes, int n_in,
                              void* d_out, int out_size, void* d_ws, size_t ws_size,
                              hipStream_t stream) {
    const float* logits = (const float*)d_in[0];
    const float* norms  = (const float*)d_in[1];
    const int*   labels = (const int*)d_in[2];
    float* out = (float*)d_out;

    float* partial = (float*)d_ws;                    // B_SZ*8 floats
    float* target  = partial + B_SZ * CHUNKS_PER_ROW; // 512
    float* plain   = target + B_SZ;                   // 512

    row_kernel<<<B_SZ * CHUNKS_PER_ROW, 256, 0, stream>>>(
        logits, norms, labels, partial, target, plain);
    final_kernel<<<1, 512, 0, stream>>>(partial, target, plain, out);
}